// Round 15
// baseline (329.362 us; speedup 1.0000x reference)
//
#include <hip/hip_runtime.h>
#include <hip/hip_bf16.h>
#include <math.h>

// Problem constants (B=4, S=2048, D=1024, H=2048, E=8)
#define M_TOK 8192   // B*S
#define N_H   2048   // H
#define K_D   1024   // D
#define N_E   8

typedef __bf16 bf16x8 __attribute__((ext_vector_type(8)));
typedef __bf16 bf16x4 __attribute__((ext_vector_type(4)));
typedef float  f32x4  __attribute__((ext_vector_type(4)));

__device__ inline f32x4 mfma16(bf16x8 a, bf16x8 b, f32x4 c) {
  return __builtin_amdgcn_mfma_f32_16x16x32_bf16(a, b, c, 0, 0, 0);
}

__device__ inline void load16_lds(const void* g, void* l) {
  __builtin_amdgcn_global_load_lds(
      (const __attribute__((address_space(1))) void*)g,
      (__attribute__((address_space(3))) void*)l, 16, 0, 0);
}

// ---------------------------------------------------------------- f32 -> bf16
__global__ __launch_bounds__(256) void cvt_kernel(const float* __restrict__ src,
                                                  __bf16* __restrict__ dst,
                                                  int n4) {
  int i = blockIdx.x * blockDim.x + threadIdx.x;
  const int stride = gridDim.x * blockDim.x;
  for (; i < n4; i += stride) {
    float4 v = ((const float4*)src)[i];
    bf16x4 o = {(__bf16)v.x, (__bf16)v.y, (__bf16)v.z, (__bf16)v.w};
    *(bf16x4*)(dst + (size_t)i * 4) = o;
  }
}

// ------------------------------------------- gate probs + X f32->bf16 (fused)
__global__ __launch_bounds__(256) void gate_kernel(const float* __restrict__ X,
                                                   const float* __restrict__ Wg,
                                                   const float* __restrict__ bg,
                                                   float* __restrict__ gate,
                                                   __bf16* __restrict__ Xb) {
  const int tid = threadIdx.x;
  const int lane = tid & 63;
  const int wv = tid >> 6;
  const int token = blockIdx.x * 4 + wv;
  const float* xrow = X + (size_t)token * K_D;

  float xr[16];
#pragma unroll
  for (int i = 0; i < 16; ++i) xr[i] = xrow[lane + i * 64];

#pragma unroll
  for (int i = 0; i < 16; ++i)
    Xb[(size_t)token * K_D + lane + i * 64] = (__bf16)xr[i];

  float l[N_E];
#pragma unroll
  for (int e = 0; e < N_E; ++e) {
    const float* wrow = Wg + e * K_D;
    float s = 0.f;
#pragma unroll
    for (int i = 0; i < 16; ++i) s += xr[i] * wrow[lane + i * 64];
#pragma unroll
    for (int off = 32; off > 0; off >>= 1) s += __shfl_xor(s, off);
    l[e] = s + bg[e];
  }
  float mx = l[0];
#pragma unroll
  for (int e = 1; e < N_E; ++e) mx = fmaxf(mx, l[e]);
  float p[N_E], den = 0.f;
#pragma unroll
  for (int e = 0; e < N_E; ++e) { p[e] = expf(l[e] - mx); den += p[e]; }
  const float inv = 1.f / den;
  if (lane == 0) {
#pragma unroll
    for (int e = 0; e < N_E; ++e) gate[(size_t)token * N_E + e] = p[e] * inv;
  }
}

// ------------------------------------------------------------------- main MoE
// r15 = r12 with ONE change: the lgkmcnt(0)+sched_barrier pin between the 12
// ds_read_b128 and the 32 MFMAs is REMOVED. The compiler now inserts its own
// counted lgkmcnt (m97 behavior), interleaving reads under the MFMA cluster —
// the ~1000 cy LDS-port phase overlaps the 1242 cy MFMA phase instead of
// running in series (r12 measured 2750 cy/phase = the sum).
// WAR audit (why the pin was NOT needed): phase sn's reads (buffer sn&3) are
// consumed by phase-sn MFMAs -> compiler's counted lgkmcnt retires them
// within the phase. The next write into that buffer is STAGE(sn+4), issued
// at phase sn+2 and landing later still — >= 2 full phases of slack.
// STAGE stays early (r6's confounder removed); literal buffer indices and
// 4 LDS buffers (r9's confounders removed). Register-neutral: one frag set.
// Everything else byte-identical to the verified r12/r14.
__global__ __launch_bounds__(512, 2) void moe_main(
    const __bf16* __restrict__ Xb, const __bf16* __restrict__ Wb,
    const float* __restrict__ gate, const float* __restrict__ be,
    float* __restrict__ out) {
  __shared__ __bf16 As[4][8192];   // 64 KB: [row 256][k 32] per k-sub buffer
  __shared__ __bf16 Bs[4][8192];   // 64 KB: rows 0-127 e0, 128-255 e1
  __shared__ float gS[256 * 8];    // 8 KB
  __shared__ float bS[8 * 128];    // 4 KB

  const int tid = threadIdx.x;
  const int lane = tid & 63;
  const int wv = tid >> 6;     // 0..7
  const int wm = wv >> 1;      // token quarter
  const int wn = wv & 1;       // h half
  const int row0 = blockIdx.x * 256;
  const int col0 = blockIdx.y * 128;

  // Preload gate/be panels (published by phase-0 barrier; read only in EPI).
  for (int i = tid; i < 2048; i += 512) gS[i] = gate[(size_t)row0 * N_E + i];
  for (int i = tid; i < 1024; i += 512)
    bS[i] = be[(size_t)(i >> 7) * N_H + col0 + (i & 127)];

  // Staging: 512 threads x 16B = 8KB per issue; 4 issues per phase:
  // A rows 0-127, A rows 128-255, B e0 rows, B e1 rows (each 256x32 halved).
  const int rA = tid >> 2;           // 0..127
  const int kk = (tid & 3) * 8;
  const __bf16* aB = Xb + (size_t)(row0 + rA) * K_D + kk;
  const __bf16* bB = Wb + (size_t)(col0 + rA) * K_D + kk;

  // Fragment read offsets (within one k-sub buffer).
  const int lr = lane & 15;
  const int lk = (lane >> 4) * 8;
  const int aOff = (wm * 64 + lr) * 32 + lk;
  const int bOff = (wn * 64 + lr) * 32 + lk;

  f32x4 fin[4][4];
#pragma unroll
  for (int m = 0; m < 4; ++m)
#pragma unroll
    for (int h = 0; h < 4; ++h) fin[m][h] = (f32x4){0.f, 0.f, 0.f, 0.f};

  f32x4 acc[4][8];
#pragma unroll
  for (int m = 0; m < 4; ++m)
#pragma unroll
    for (int n = 0; n < 8; ++n) acc[m][n] = (f32x4){0.f, 0.f, 0.f, 0.f};

  // Stage k-sub sn into buffer q. sn = pair*32 + ks; pair stride = 2*N_H*K_D.
  auto STAGE = [&](int sn, int q) {
    const int k0 = (sn & 31) << 5;
    const size_t pOff = (size_t)(sn >> 5) << 22;
    load16_lds(aB + k0, &As[q][tid * 8]);
    load16_lds(aB + (size_t)128 * K_D + k0, &As[q][4096 + tid * 8]);
    load16_lds(bB + pOff + k0, &Bs[q][tid * 8]);
    load16_lds(bB + pOff + (size_t)N_H * K_D + k0, &Bs[q][4096 + tid * 8]);
  };

  // Pair epilogue: fin += g_e0*LR(acc_e0 + be) + g_e1*LR(acc_e1 + be); acc=0.
  auto EPI = [&](int p) {
    const int e0 = p * 2;
#pragma unroll
    for (int m = 0; m < 4; ++m) {
#pragma unroll
      for (int j = 0; j < 4; ++j) {
        const int r = wm * 64 + m * 16 + (lane >> 4) * 4 + j;  // 0..255
        const float g0 = gS[r * 8 + e0];
        const float g1 = gS[r * 8 + e0 + 1];
#pragma unroll
        for (int h = 0; h < 4; ++h) {
          const int c = wn * 64 + h * 16 + lr;                 // 0..127
          float v0 = acc[m][h][j] + bS[e0 * 128 + c];
          v0 = (v0 >= 0.f) ? v0 : 0.01f * v0;
          float v1 = acc[m][4 + h][j] + bS[(e0 + 1) * 128 + c];
          v1 = (v1 >= 0.f) ? v1 : 0.01f * v1;
          fin[m][h][j] += g0 * v0 + g1 * v1;
        }
      }
    }
#pragma unroll
    for (int m = 0; m < 4; ++m)
#pragma unroll
      for (int n = 0; n < 8; ++n) acc[m][n] = (f32x4){0.f, 0.f, 0.f, 0.f};
  };

  // One phase. q = sn&3 (literal at every call site). doStage: sn+2 <= 127.
  auto PHASE = [&](int sn, int q, bool doStage, bool lastPhase) {
    if (lastPhase)
      asm volatile("s_waitcnt vmcnt(0)" ::: "memory");
    else
      asm volatile("s_waitcnt vmcnt(4)" ::: "memory");  // own sn loads landed
    __builtin_amdgcn_s_barrier();        // all waves' sn loads published
    __builtin_amdgcn_sched_barrier(0);   // reads stay below the barrier

    bf16x8 af[4], bfr[8];
#pragma unroll
    for (int m = 0; m < 4; ++m)
      af[m] = *(const bf16x8*)(&As[q][aOff + m * 512]);
#pragma unroll
    for (int n = 0; n < 8; ++n)
      bfr[n] = *(const bf16x8*)(&Bs[q][bOff + ((n >> 2) * 128 + (n & 3) * 16) * 32]);
    // NO lgkmcnt(0) pin here (r15 change): compiler inserts counted lgkmcnt,
    // interleaving the reads under the MFMA cluster below.

    if (doStage) STAGE(sn + 2, (q + 2) & 3);  // target last read at sn-2: safe

    __builtin_amdgcn_s_setprio(1);
#pragma unroll
    for (int n = 0; n < 8; ++n)
#pragma unroll
      for (int m = 0; m < 4; ++m)
        acc[m][n] = mfma16(af[m], bfr[n], acc[m][n]);
    __builtin_amdgcn_s_setprio(0);

    if ((sn & 31) == 31) EPI(sn >> 5);
  };

  STAGE(0, 0);
  STAGE(1, 1);  // 8 own loads in flight; phase 0 waits vmcnt(4)

#pragma unroll 1
  for (int t4 = 0; t4 < 31; ++t4) {
    const int sn = t4 * 4;
    PHASE(sn + 0, 0, true, false);
    PHASE(sn + 1, 1, true, false);
    PHASE(sn + 2, 2, true, false);
    PHASE(sn + 3, 3, true, false);
  }
  PHASE(124, 0, true, false);   // stages 126
  PHASE(125, 1, true, false);   // stages 127
  PHASE(126, 2, false, false);  // vmcnt(4): 126 landed, 127 in flight
  PHASE(127, 3, false, true);   // vmcnt(0) + EPI(3)

  // C write (fp32 out)
#pragma unroll
  for (int m = 0; m < 4; ++m) {
#pragma unroll
    for (int j = 0; j < 4; ++j) {
      const size_t r = (size_t)(row0 + wm * 64 + m * 16 + (lane >> 4) * 4 + j);
#pragma unroll
      for (int h = 0; h < 4; ++h) {
        out[r * N_H + col0 + wn * 64 + h * 16 + lr] = fin[m][h][j];
      }
    }
  }
}

extern "C" void kernel_launch(void* const* d_in, const int* in_sizes, int n_in,
                              void* d_out, int out_size, void* d_ws, size_t ws_size,
                              hipStream_t stream) {
  const float* X  = (const float*)d_in[0];  // [8192,1024]
  const float* Wg = (const float*)d_in[1];  // [8,1024]
  const float* bg = (const float*)d_in[2];  // [8]
  const float* We = (const float*)d_in[3];  // [8,2048,1024]
  const float* be = (const float*)d_in[4];  // [8,2048]
  float* out = (float*)d_out;               // [8192,2048]

  // Workspace layout
  char* ws = (char*)d_ws;
  __bf16* Xb   = (__bf16*)(ws);                               // 16 MB
  __bf16* Wb   = (__bf16*)(ws + (size_t)16 * 1024 * 1024);    // 32 MB
  float*  gate = (float*)(ws + (size_t)48 * 1024 * 1024);     // 256 KB

  // 1) We f32 -> bf16
  cvt_kernel<<<2048, 256, 0, stream>>>(We, Wb, (N_E * N_H * K_D) / 4);

  // 2) gate probs + X f32->bf16 (fused)
  gate_kernel<<<M_TOK / 4, 256, 0, stream>>>(X, Wg, bg, gate, Xb);

  // 3) fused expert GEMM + gate-weighted reduction
  dim3 grid(M_TOK / 256, N_H / 128);
  moe_main<<<grid, 512, 0, stream>>>(Xb, Wb, gate, be, out);
}

// Round 16
// 302.792 us; speedup vs baseline: 1.0878x; 1.0878x over previous
//
#include <hip/hip_runtime.h>
#include <hip/hip_bf16.h>
#include <math.h>

// Problem constants (B=4, S=2048, D=1024, H=2048, E=8)
#define M_TOK 8192   // B*S
#define N_H   2048   // H
#define K_D   1024   // D
#define N_E   8

typedef __bf16 bf16x8 __attribute__((ext_vector_type(8)));
typedef __bf16 bf16x4 __attribute__((ext_vector_type(4)));
typedef float  f32x4  __attribute__((ext_vector_type(4)));

__device__ inline f32x4 mfma16(bf16x8 a, bf16x8 b, f32x4 c) {
  return __builtin_amdgcn_mfma_f32_16x16x32_bf16(a, b, c, 0, 0, 0);
}

__device__ inline void load16_lds(const void* g, void* l) {
  __builtin_amdgcn_global_load_lds(
      (const __attribute__((address_space(1))) void*)g,
      (__attribute__((address_space(3))) void*)l, 16, 0, 0);
}

// ---------------------------------------------------------------- f32 -> bf16
__global__ __launch_bounds__(256) void cvt_kernel(const float* __restrict__ src,
                                                  __bf16* __restrict__ dst,
                                                  int n4) {
  int i = blockIdx.x * blockDim.x + threadIdx.x;
  const int stride = gridDim.x * blockDim.x;
  for (; i < n4; i += stride) {
    float4 v = ((const float4*)src)[i];
    bf16x4 o = {(__bf16)v.x, (__bf16)v.y, (__bf16)v.z, (__bf16)v.w};
    *(bf16x4*)(dst + (size_t)i * 4) = o;
  }
}

// ------------------------------------------- gate probs + X f32->bf16 (fused)
__global__ __launch_bounds__(256) void gate_kernel(const float* __restrict__ X,
                                                   const float* __restrict__ Wg,
                                                   const float* __restrict__ bg,
                                                   float* __restrict__ gate,
                                                   __bf16* __restrict__ Xb) {
  const int tid = threadIdx.x;
  const int lane = tid & 63;
  const int wv = tid >> 6;
  const int token = blockIdx.x * 4 + wv;
  const float* xrow = X + (size_t)token * K_D;

  float xr[16];
#pragma unroll
  for (int i = 0; i < 16; ++i) xr[i] = xrow[lane + i * 64];

#pragma unroll
  for (int i = 0; i < 16; ++i)
    Xb[(size_t)token * K_D + lane + i * 64] = (__bf16)xr[i];

  float l[N_E];
#pragma unroll
  for (int e = 0; e < N_E; ++e) {
    const float* wrow = Wg + e * K_D;
    float s = 0.f;
#pragma unroll
    for (int i = 0; i < 16; ++i) s += xr[i] * wrow[lane + i * 64];
#pragma unroll
    for (int off = 32; off > 0; off >>= 1) s += __shfl_xor(s, off);
    l[e] = s + bg[e];
  }
  float mx = l[0];
#pragma unroll
  for (int e = 1; e < N_E; ++e) mx = fmaxf(mx, l[e]);
  float p[N_E], den = 0.f;
#pragma unroll
  for (int e = 0; e < N_E; ++e) { p[e] = expf(l[e] - mx); den += p[e]; }
  const float inv = 1.f / den;
  if (lane == 0) {
#pragma unroll
    for (int e = 0; e < N_E; ++e) gate[(size_t)token * N_E + e] = p[e] * inv;
  }
}

// ------------------------------------------------------------------- main MoE
// FINAL: r12 verbatim — the verified best (moe_main 293.6 us, total ~304.5,
// 940 TF, MfmaUtil 41.5%). 256-token tall tile, counted-vmcnt phase pipeline:
// block = 256 tokens x 128 h-cols x 2 staged experts, 8 waves; per-wave phase
// = 12 ds_read_b128 + lgkmcnt(0) pin + 32 MFMA (acc[4][8], fin[4][4]);
// 128 phases (4 expert-pairs x 32 k-subs); 4 k-sub LDS buffers -> one
// barrier/phase, vmcnt(4) steady-state (never drains in-loop).
// Plateau evidence: 9 schedule variants tested; every perturbation regressed
// (stage-late 316, unpinned 2-buf 316, 3-buf runtime-idx 325, unpinned 4-buf
// 330, T1 swizzle 338) or spilled (3-buf unrolled, 3-blocks/CU, dual frag
// sets). The pure-phase pin + setprio lets the CU alternate whole waves
// between read-burst and MFMA-burst; compiler interleaves measurably lose.
// Register wall: fin+acc = 192 regs leaves room for exactly one frag set in
// the 256/wave budget -> m201-style cross-phase register pipelining (the
// documented escape past ~917 TF) is infeasible for this fused epilogue.
__global__ __launch_bounds__(512, 2) void moe_main(
    const __bf16* __restrict__ Xb, const __bf16* __restrict__ Wb,
    const float* __restrict__ gate, const float* __restrict__ be,
    float* __restrict__ out) {
  __shared__ __bf16 As[4][8192];   // 64 KB: [row 256][k 32] per k-sub buffer
  __shared__ __bf16 Bs[4][8192];   // 64 KB: rows 0-127 e0, 128-255 e1
  __shared__ float gS[256 * 8];    // 8 KB
  __shared__ float bS[8 * 128];    // 4 KB

  const int tid = threadIdx.x;
  const int lane = tid & 63;
  const int wv = tid >> 6;     // 0..7
  const int wm = wv >> 1;      // token quarter
  const int wn = wv & 1;       // h half
  const int row0 = blockIdx.x * 256;
  const int col0 = blockIdx.y * 128;

  // Preload gate/be panels (published by phase-0 barrier; read only in EPI).
  for (int i = tid; i < 2048; i += 512) gS[i] = gate[(size_t)row0 * N_E + i];
  for (int i = tid; i < 1024; i += 512)
    bS[i] = be[(size_t)(i >> 7) * N_H + col0 + (i & 127)];

  // Staging: 512 threads x 16B = 8KB per issue; 4 issues per phase:
  // A rows 0-127, A rows 128-255, B e0 rows, B e1 rows (each 256x32 halved).
  const int rA = tid >> 2;           // 0..127
  const int kk = (tid & 3) * 8;
  const __bf16* aB = Xb + (size_t)(row0 + rA) * K_D + kk;
  const __bf16* bB = Wb + (size_t)(col0 + rA) * K_D + kk;

  // Fragment read offsets (within one k-sub buffer).
  const int lr = lane & 15;
  const int lk = (lane >> 4) * 8;
  const int aOff = (wm * 64 + lr) * 32 + lk;
  const int bOff = (wn * 64 + lr) * 32 + lk;

  f32x4 fin[4][4];
#pragma unroll
  for (int m = 0; m < 4; ++m)
#pragma unroll
    for (int h = 0; h < 4; ++h) fin[m][h] = (f32x4){0.f, 0.f, 0.f, 0.f};

  f32x4 acc[4][8];
#pragma unroll
  for (int m = 0; m < 4; ++m)
#pragma unroll
    for (int n = 0; n < 8; ++n) acc[m][n] = (f32x4){0.f, 0.f, 0.f, 0.f};

  // Stage k-sub sn into buffer q. sn = pair*32 + ks; pair stride = 2*N_H*K_D.
  auto STAGE = [&](int sn, int q) {
    const int k0 = (sn & 31) << 5;
    const size_t pOff = (size_t)(sn >> 5) << 22;
    load16_lds(aB + k0, &As[q][tid * 8]);
    load16_lds(aB + (size_t)128 * K_D + k0, &As[q][4096 + tid * 8]);
    load16_lds(bB + pOff + k0, &Bs[q][tid * 8]);
    load16_lds(bB + pOff + (size_t)N_H * K_D + k0, &Bs[q][4096 + tid * 8]);
  };

  // Pair epilogue: fin += g_e0*LR(acc_e0 + be) + g_e1*LR(acc_e1 + be); acc=0.
  auto EPI = [&](int p) {
    const int e0 = p * 2;
#pragma unroll
    for (int m = 0; m < 4; ++m) {
#pragma unroll
      for (int j = 0; j < 4; ++j) {
        const int r = wm * 64 + m * 16 + (lane >> 4) * 4 + j;  // 0..255
        const float g0 = gS[r * 8 + e0];
        const float g1 = gS[r * 8 + e0 + 1];
#pragma unroll
        for (int h = 0; h < 4; ++h) {
          const int c = wn * 64 + h * 16 + lr;                 // 0..127
          float v0 = acc[m][h][j] + bS[e0 * 128 + c];
          v0 = (v0 >= 0.f) ? v0 : 0.01f * v0;
          float v1 = acc[m][4 + h][j] + bS[(e0 + 1) * 128 + c];
          v1 = (v1 >= 0.f) ? v1 : 0.01f * v1;
          fin[m][h][j] += g0 * v0 + g1 * v1;
        }
      }
    }
#pragma unroll
    for (int m = 0; m < 4; ++m)
#pragma unroll
      for (int n = 0; n < 8; ++n) acc[m][n] = (f32x4){0.f, 0.f, 0.f, 0.f};
  };

  // One phase. q = sn&3 (literal at every call site). doStage: sn+2 <= 127.
  auto PHASE = [&](int sn, int q, bool doStage, bool lastPhase) {
    if (lastPhase)
      asm volatile("s_waitcnt vmcnt(0)" ::: "memory");
    else
      asm volatile("s_waitcnt vmcnt(4)" ::: "memory");  // own sn loads landed
    __builtin_amdgcn_s_barrier();        // all waves' sn loads published
    __builtin_amdgcn_sched_barrier(0);   // reads stay below the barrier

    bf16x8 af[4], bfr[8];
#pragma unroll
    for (int m = 0; m < 4; ++m)
      af[m] = *(const bf16x8*)(&As[q][aOff + m * 512]);
#pragma unroll
    for (int n = 0; n < 8; ++n)
      bfr[n] = *(const bf16x8*)(&Bs[q][bOff + ((n >> 2) * 128 + (n & 3) * 16) * 32]);
    asm volatile("s_waitcnt lgkmcnt(0)" ::: "memory");   // frag reads retired
    __builtin_amdgcn_sched_barrier(0);                   // pure-phase boundary

    if (doStage) STAGE(sn + 2, (q + 2) & 3);  // target last read at sn-2: safe

    __builtin_amdgcn_s_setprio(1);
#pragma unroll
    for (int n = 0; n < 8; ++n)
#pragma unroll
      for (int m = 0; m < 4; ++m)
        acc[m][n] = mfma16(af[m], bfr[n], acc[m][n]);
    __builtin_amdgcn_s_setprio(0);

    if ((sn & 31) == 31) EPI(sn >> 5);
  };

  STAGE(0, 0);
  STAGE(1, 1);  // 8 own loads in flight; phase 0 waits vmcnt(4)

#pragma unroll 1
  for (int t4 = 0; t4 < 31; ++t4) {
    const int sn = t4 * 4;
    PHASE(sn + 0, 0, true, false);
    PHASE(sn + 1, 1, true, false);
    PHASE(sn + 2, 2, true, false);
    PHASE(sn + 3, 3, true, false);
  }
  PHASE(124, 0, true, false);   // stages 126
  PHASE(125, 1, true, false);   // stages 127
  PHASE(126, 2, false, false);  // vmcnt(4): 126 landed, 127 in flight
  PHASE(127, 3, false, true);   // vmcnt(0) + EPI(3)

  // C write (fp32 out)
#pragma unroll
  for (int m = 0; m < 4; ++m) {
#pragma unroll
    for (int j = 0; j < 4; ++j) {
      const size_t r = (size_t)(row0 + wm * 64 + m * 16 + (lane >> 4) * 4 + j);
#pragma unroll
      for (int h = 0; h < 4; ++h) {
        out[r * N_H + col0 + wn * 64 + h * 16 + lr] = fin[m][h][j];
      }
    }
  }
}

extern "C" void kernel_launch(void* const* d_in, const int* in_sizes, int n_in,
                              void* d_out, int out_size, void* d_ws, size_t ws_size,
                              hipStream_t stream) {
  const float* X  = (const float*)d_in[0];  // [8192,1024]
  const float* Wg = (const float*)d_in[1];  // [8,1024]
  const float* bg = (const float*)d_in[2];  // [8]
  const float* We = (const float*)d_in[3];  // [8,2048,1024]
  const float* be = (const float*)d_in[4];  // [8,2048]
  float* out = (float*)d_out;               // [8192,2048]

  // Workspace layout
  char* ws = (char*)d_ws;
  __bf16* Xb   = (__bf16*)(ws);                               // 16 MB
  __bf16* Wb   = (__bf16*)(ws + (size_t)16 * 1024 * 1024);    // 32 MB
  float*  gate = (float*)(ws + (size_t)48 * 1024 * 1024);     // 256 KB

  // 1) We f32 -> bf16
  cvt_kernel<<<2048, 256, 0, stream>>>(We, Wb, (N_E * N_H * K_D) / 4);

  // 2) gate probs + X f32->bf16 (fused)
  gate_kernel<<<M_TOK / 4, 256, 0, stream>>>(X, Wg, bg, gate, Xb);

  // 3) fused expert GEMM + gate-weighted reduction
  dim3 grid(M_TOK / 256, N_H / 128);
  moe_main<<<grid, 512, 0, stream>>>(Xb, Wb, gate, be, out);
}

// Round 17
// 298.506 us; speedup vs baseline: 1.1034x; 1.0144x over previous
//
#include <hip/hip_runtime.h>
#include <hip/hip_bf16.h>
#include <math.h>

// Problem constants (B=4, S=2048, D=1024, H=2048, E=8)
#define M_TOK 8192   // B*S
#define N_H   2048   // H
#define K_D   1024   // D
#define N_E   8

typedef __bf16 bf16x8 __attribute__((ext_vector_type(8)));
typedef __bf16 bf16x4 __attribute__((ext_vector_type(4)));
typedef float  f32x4  __attribute__((ext_vector_type(4)));

__device__ inline f32x4 mfma16(bf16x8 a, bf16x8 b, f32x4 c) {
  return __builtin_amdgcn_mfma_f32_16x16x32_bf16(a, b, c, 0, 0, 0);
}

__device__ inline void load16_lds(const void* g, void* l) {
  __builtin_amdgcn_global_load_lds(
      (const __attribute__((address_space(1))) void*)g,
      (__attribute__((address_space(3))) void*)l, 16, 0, 0);
}

// ---------------------------------------------------------------- f32 -> bf16
__global__ __launch_bounds__(256) void cvt_kernel(const float* __restrict__ src,
                                                  __bf16* __restrict__ dst,
                                                  int n4) {
  int i = blockIdx.x * blockDim.x + threadIdx.x;
  const int stride = gridDim.x * blockDim.x;
  for (; i < n4; i += stride) {
    float4 v = ((const float4*)src)[i];
    bf16x4 o = {(__bf16)v.x, (__bf16)v.y, (__bf16)v.z, (__bf16)v.w};
    *(bf16x4*)(dst + (size_t)i * 4) = o;
  }
}

// ------------------------------------------- gate probs + X f32->bf16 (fused)
__global__ __launch_bounds__(256) void gate_kernel(const float* __restrict__ X,
                                                   const float* __restrict__ Wg,
                                                   const float* __restrict__ bg,
                                                   float* __restrict__ gate,
                                                   __bf16* __restrict__ Xb) {
  const int tid = threadIdx.x;
  const int lane = tid & 63;
  const int wv = tid >> 6;
  const int token = blockIdx.x * 4 + wv;
  const float* xrow = X + (size_t)token * K_D;

  float xr[16];
#pragma unroll
  for (int i = 0; i < 16; ++i) xr[i] = xrow[lane + i * 64];

#pragma unroll
  for (int i = 0; i < 16; ++i)
    Xb[(size_t)token * K_D + lane + i * 64] = (__bf16)xr[i];

  float l[N_E];
#pragma unroll
  for (int e = 0; e < N_E; ++e) {
    const float* wrow = Wg + e * K_D;
    float s = 0.f;
#pragma unroll
    for (int i = 0; i < 16; ++i) s += xr[i] * wrow[lane + i * 64];
#pragma unroll
    for (int off = 32; off > 0; off >>= 1) s += __shfl_xor(s, off);
    l[e] = s + bg[e];
  }
  float mx = l[0];
#pragma unroll
  for (int e = 1; e < N_E; ++e) mx = fmaxf(mx, l[e]);
  float p[N_E], den = 0.f;
#pragma unroll
  for (int e = 0; e < N_E; ++e) { p[e] = expf(l[e] - mx); den += p[e]; }
  const float inv = 1.f / den;
  if (lane == 0) {
#pragma unroll
    for (int e = 0; e < N_E; ++e) gate[(size_t)token * N_E + e] = p[e] * inv;
  }
}

// ------------------------------------------------------------------- main MoE
// r17 = r12 with ONE refinement: the single lgkmcnt(0) pin is split into a
// COUNTED pair. All 12 ds_read_b128 issue up front (LDS port fills
// continuously); s_waitcnt lgkmcnt(4) releases the first 8 (af[4]+bfr[0..3],
// in-order retirement) -> MFMA n=0..3 runs while bfr[4..7]'s port time and
// latency drain; lgkmcnt(0) then releases MFMA n=4..7. Phase discipline,
// STAGE placement, barriers, setprio identical to the verified r12.
// Correctness: LDS returns are in-order AND the compiler still inserts its
// own waits before frag uses — the asm waits only add constraints.
__global__ __launch_bounds__(512, 2) void moe_main(
    const __bf16* __restrict__ Xb, const __bf16* __restrict__ Wb,
    const float* __restrict__ gate, const float* __restrict__ be,
    float* __restrict__ out) {
  __shared__ __bf16 As[4][8192];   // 64 KB: [row 256][k 32] per k-sub buffer
  __shared__ __bf16 Bs[4][8192];   // 64 KB: rows 0-127 e0, 128-255 e1
  __shared__ float gS[256 * 8];    // 8 KB
  __shared__ float bS[8 * 128];    // 4 KB

  const int tid = threadIdx.x;
  const int lane = tid & 63;
  const int wv = tid >> 6;     // 0..7
  const int wm = wv >> 1;      // token quarter
  const int wn = wv & 1;       // h half
  const int row0 = blockIdx.x * 256;
  const int col0 = blockIdx.y * 128;

  // Preload gate/be panels (published by phase-0 barrier; read only in EPI).
  for (int i = tid; i < 2048; i += 512) gS[i] = gate[(size_t)row0 * N_E + i];
  for (int i = tid; i < 1024; i += 512)
    bS[i] = be[(size_t)(i >> 7) * N_H + col0 + (i & 127)];

  // Staging: 512 threads x 16B = 8KB per issue; 4 issues per phase:
  // A rows 0-127, A rows 128-255, B e0 rows, B e1 rows (each 256x32 halved).
  const int rA = tid >> 2;           // 0..127
  const int kk = (tid & 3) * 8;
  const __bf16* aB = Xb + (size_t)(row0 + rA) * K_D + kk;
  const __bf16* bB = Wb + (size_t)(col0 + rA) * K_D + kk;

  // Fragment read offsets (within one k-sub buffer).
  const int lr = lane & 15;
  const int lk = (lane >> 4) * 8;
  const int aOff = (wm * 64 + lr) * 32 + lk;
  const int bOff = (wn * 64 + lr) * 32 + lk;

  f32x4 fin[4][4];
#pragma unroll
  for (int m = 0; m < 4; ++m)
#pragma unroll
    for (int h = 0; h < 4; ++h) fin[m][h] = (f32x4){0.f, 0.f, 0.f, 0.f};

  f32x4 acc[4][8];
#pragma unroll
  for (int m = 0; m < 4; ++m)
#pragma unroll
    for (int n = 0; n < 8; ++n) acc[m][n] = (f32x4){0.f, 0.f, 0.f, 0.f};

  // Stage k-sub sn into buffer q. sn = pair*32 + ks; pair stride = 2*N_H*K_D.
  auto STAGE = [&](int sn, int q) {
    const int k0 = (sn & 31) << 5;
    const size_t pOff = (size_t)(sn >> 5) << 22;
    load16_lds(aB + k0, &As[q][tid * 8]);
    load16_lds(aB + (size_t)128 * K_D + k0, &As[q][4096 + tid * 8]);
    load16_lds(bB + pOff + k0, &Bs[q][tid * 8]);
    load16_lds(bB + pOff + (size_t)N_H * K_D + k0, &Bs[q][4096 + tid * 8]);
  };

  // Pair epilogue: fin += g_e0*LR(acc_e0 + be) + g_e1*LR(acc_e1 + be); acc=0.
  auto EPI = [&](int p) {
    const int e0 = p * 2;
#pragma unroll
    for (int m = 0; m < 4; ++m) {
#pragma unroll
      for (int j = 0; j < 4; ++j) {
        const int r = wm * 64 + m * 16 + (lane >> 4) * 4 + j;  // 0..255
        const float g0 = gS[r * 8 + e0];
        const float g1 = gS[r * 8 + e0 + 1];
#pragma unroll
        for (int h = 0; h < 4; ++h) {
          const int c = wn * 64 + h * 16 + lr;                 // 0..127
          float v0 = acc[m][h][j] + bS[e0 * 128 + c];
          v0 = (v0 >= 0.f) ? v0 : 0.01f * v0;
          float v1 = acc[m][4 + h][j] + bS[(e0 + 1) * 128 + c];
          v1 = (v1 >= 0.f) ? v1 : 0.01f * v1;
          fin[m][h][j] += g0 * v0 + g1 * v1;
        }
      }
    }
#pragma unroll
    for (int m = 0; m < 4; ++m)
#pragma unroll
      for (int n = 0; n < 8; ++n) acc[m][n] = (f32x4){0.f, 0.f, 0.f, 0.f};
  };

  // One phase. q = sn&3 (literal at every call site). doStage: sn+2 <= 127.
  auto PHASE = [&](int sn, int q, bool doStage, bool lastPhase) {
    if (lastPhase)
      asm volatile("s_waitcnt vmcnt(0)" ::: "memory");
    else
      asm volatile("s_waitcnt vmcnt(4)" ::: "memory");  // own sn loads landed
    __builtin_amdgcn_s_barrier();        // all waves' sn loads published
    __builtin_amdgcn_sched_barrier(0);   // reads stay below the barrier

    bf16x8 af[4], bfr[8];
#pragma unroll
    for (int m = 0; m < 4; ++m)
      af[m] = *(const bf16x8*)(&As[q][aOff + m * 512]);
#pragma unroll
    for (int n = 0; n < 8; ++n)
      bfr[n] = *(const bf16x8*)(&Bs[q][bOff + ((n >> 2) * 128 + (n & 3) * 16) * 32]);
    asm volatile("s_waitcnt lgkmcnt(4)" ::: "memory");   // first 8 reads done
    __builtin_amdgcn_sched_barrier(0);                   // pin MFMA group 1 below

    if (doStage) STAGE(sn + 2, (q + 2) & 3);  // target last read at sn-2: safe

    __builtin_amdgcn_s_setprio(1);
#pragma unroll
    for (int n = 0; n < 4; ++n)                // group 1: af x bfr[0..3]
#pragma unroll
      for (int m = 0; m < 4; ++m)
        acc[m][n] = mfma16(af[m], bfr[n], acc[m][n]);
    __builtin_amdgcn_s_setprio(0);

    asm volatile("s_waitcnt lgkmcnt(0)" ::: "memory");   // last 4 reads done
    __builtin_amdgcn_sched_barrier(0);                   // pin MFMA group 2 below

    __builtin_amdgcn_s_setprio(1);
#pragma unroll
    for (int n = 4; n < 8; ++n)                // group 2: af x bfr[4..7]
#pragma unroll
      for (int m = 0; m < 4; ++m)
        acc[m][n] = mfma16(af[m], bfr[n], acc[m][n]);
    __builtin_amdgcn_s_setprio(0);

    if ((sn & 31) == 31) EPI(sn >> 5);
  };

  STAGE(0, 0);
  STAGE(1, 1);  // 8 own loads in flight; phase 0 waits vmcnt(4)

#pragma unroll 1
  for (int t4 = 0; t4 < 31; ++t4) {
    const int sn = t4 * 4;
    PHASE(sn + 0, 0, true, false);
    PHASE(sn + 1, 1, true, false);
    PHASE(sn + 2, 2, true, false);
    PHASE(sn + 3, 3, true, false);
  }
  PHASE(124, 0, true, false);   // stages 126
  PHASE(125, 1, true, false);   // stages 127
  PHASE(126, 2, false, false);  // vmcnt(4): 126 landed, 127 in flight
  PHASE(127, 3, false, true);   // vmcnt(0) + EPI(3)

  // C write (fp32 out)
#pragma unroll
  for (int m = 0; m < 4; ++m) {
#pragma unroll
    for (int j = 0; j < 4; ++j) {
      const size_t r = (size_t)(row0 + wm * 64 + m * 16 + (lane >> 4) * 4 + j);
#pragma unroll
      for (int h = 0; h < 4; ++h) {
        out[r * N_H + col0 + wn * 64 + h * 16 + lr] = fin[m][h][j];
      }
    }
  }
}

extern "C" void kernel_launch(void* const* d_in, const int* in_sizes, int n_in,
                              void* d_out, int out_size, void* d_ws, size_t ws_size,
                              hipStream_t stream) {
  const float* X  = (const float*)d_in[0];  // [8192,1024]
  const float* Wg = (const float*)d_in[1];  // [8,1024]
  const float* bg = (const float*)d_in[2];  // [8]
  const float* We = (const float*)d_in[3];  // [8,2048,1024]
  const float* be = (const float*)d_in[4];  // [8,2048]
  float* out = (float*)d_out;               // [8192,2048]

  // Workspace layout
  char* ws = (char*)d_ws;
  __bf16* Xb   = (__bf16*)(ws);                               // 16 MB
  __bf16* Wb   = (__bf16*)(ws + (size_t)16 * 1024 * 1024);    // 32 MB
  float*  gate = (float*)(ws + (size_t)48 * 1024 * 1024);     // 256 KB

  // 1) We f32 -> bf16
  cvt_kernel<<<2048, 256, 0, stream>>>(We, Wb, (N_E * N_H * K_D) / 4);

  // 2) gate probs + X f32->bf16 (fused)
  gate_kernel<<<M_TOK / 4, 256, 0, stream>>>(X, Wg, bg, gate, Xb);

  // 3) fused expert GEMM + gate-weighted reduction
  dim3 grid(M_TOK / 256, N_H / 128);
  moe_main<<<grid, 512, 0, stream>>>(Xb, Wb, gate, be, out);
}

// Round 18
// 296.992 us; speedup vs baseline: 1.1090x; 1.0051x over previous
//
#include <hip/hip_runtime.h>
#include <hip/hip_bf16.h>
#include <math.h>

// Problem constants (B=4, S=2048, D=1024, H=2048, E=8)
#define M_TOK 8192   // B*S
#define N_H   2048   // H
#define K_D   1024   // D
#define N_E   8

typedef __bf16 bf16x8 __attribute__((ext_vector_type(8)));
typedef __bf16 bf16x4 __attribute__((ext_vector_type(4)));
typedef float  f32x4  __attribute__((ext_vector_type(4)));

__device__ inline f32x4 mfma16(bf16x8 a, bf16x8 b, f32x4 c) {
  return __builtin_amdgcn_mfma_f32_16x16x32_bf16(a, b, c, 0, 0, 0);
}

__device__ inline void load16_lds(const void* g, void* l) {
  __builtin_amdgcn_global_load_lds(
      (const __attribute__((address_space(1))) void*)g,
      (__attribute__((address_space(3))) void*)l, 16, 0, 0);
}

// ---------------------------------------------------------------- f32 -> bf16
__global__ __launch_bounds__(256) void cvt_kernel(const float* __restrict__ src,
                                                  __bf16* __restrict__ dst,
                                                  int n4) {
  int i = blockIdx.x * blockDim.x + threadIdx.x;
  const int stride = gridDim.x * blockDim.x;
  for (; i < n4; i += stride) {
    float4 v = ((const float4*)src)[i];
    bf16x4 o = {(__bf16)v.x, (__bf16)v.y, (__bf16)v.z, (__bf16)v.w};
    *(bf16x4*)(dst + (size_t)i * 4) = o;
  }
}

// ------------------------------------------- gate probs + X f32->bf16 (fused)
__global__ __launch_bounds__(256) void gate_kernel(const float* __restrict__ X,
                                                   const float* __restrict__ Wg,
                                                   const float* __restrict__ bg,
                                                   float* __restrict__ gate,
                                                   __bf16* __restrict__ Xb) {
  const int tid = threadIdx.x;
  const int lane = tid & 63;
  const int wv = tid >> 6;
  const int token = blockIdx.x * 4 + wv;
  const float* xrow = X + (size_t)token * K_D;

  float xr[16];
#pragma unroll
  for (int i = 0; i < 16; ++i) xr[i] = xrow[lane + i * 64];

#pragma unroll
  for (int i = 0; i < 16; ++i)
    Xb[(size_t)token * K_D + lane + i * 64] = (__bf16)xr[i];

  float l[N_E];
#pragma unroll
  for (int e = 0; e < N_E; ++e) {
    const float* wrow = Wg + e * K_D;
    float s = 0.f;
#pragma unroll
    for (int i = 0; i < 16; ++i) s += xr[i] * wrow[lane + i * 64];
#pragma unroll
    for (int off = 32; off > 0; off >>= 1) s += __shfl_xor(s, off);
    l[e] = s + bg[e];
  }
  float mx = l[0];
#pragma unroll
  for (int e = 1; e < N_E; ++e) mx = fmaxf(mx, l[e]);
  float p[N_E], den = 0.f;
#pragma unroll
  for (int e = 0; e < N_E; ++e) { p[e] = expf(l[e] - mx); den += p[e]; }
  const float inv = 1.f / den;
  if (lane == 0) {
#pragma unroll
    for (int e = 0; e < N_E; ++e) gate[(size_t)token * N_E + e] = p[e] * inv;
  }
}

// ------------------------------------------------------------------- main MoE
// r18 = r17 with the counted-lgkm split extended to the MAXIMAL LADDER.
// Reads retire in order af[0..3], bfr[0..7]; MFMA group n needs af[*]+bfr[n]
// = first 5+n retirements -> s_waitcnt lgkmcnt(7-n). Ladder:
//   issue 12 ds_read_b128
//   lgkmcnt(7) -> STAGE -> MFMA n=0
//   lgkmcnt(6) -> n=1 ... lgkmcnt(0) -> n=7
// Each 4-MFMA group (~20 cy) covers one read's port time (~12 cy) — both
// pipes continuously fed; initial serial wait shrinks from 8 reads (r17) to
// 5. Phase discipline / barriers / vmcnt schedule / STAGE slot identical to
// the verified r17 (which won +18 us with the 2-way split of this mechanism).
// r17 ladder history: r12 single pin 293.6 -> r17 2-way split 275.4.
__global__ __launch_bounds__(512, 2) void moe_main(
    const __bf16* __restrict__ Xb, const __bf16* __restrict__ Wb,
    const float* __restrict__ gate, const float* __restrict__ be,
    float* __restrict__ out) {
  __shared__ __bf16 As[4][8192];   // 64 KB: [row 256][k 32] per k-sub buffer
  __shared__ __bf16 Bs[4][8192];   // 64 KB: rows 0-127 e0, 128-255 e1
  __shared__ float gS[256 * 8];    // 8 KB
  __shared__ float bS[8 * 128];    // 4 KB

  const int tid = threadIdx.x;
  const int lane = tid & 63;
  const int wv = tid >> 6;     // 0..7
  const int wm = wv >> 1;      // token quarter
  const int wn = wv & 1;       // h half
  const int row0 = blockIdx.x * 256;
  const int col0 = blockIdx.y * 128;

  // Preload gate/be panels (published by phase-0 barrier; read only in EPI).
  for (int i = tid; i < 2048; i += 512) gS[i] = gate[(size_t)row0 * N_E + i];
  for (int i = tid; i < 1024; i += 512)
    bS[i] = be[(size_t)(i >> 7) * N_H + col0 + (i & 127)];

  // Staging: 512 threads x 16B = 8KB per issue; 4 issues per phase:
  // A rows 0-127, A rows 128-255, B e0 rows, B e1 rows (each 256x32 halved).
  const int rA = tid >> 2;           // 0..127
  const int kk = (tid & 3) * 8;
  const __bf16* aB = Xb + (size_t)(row0 + rA) * K_D + kk;
  const __bf16* bB = Wb + (size_t)(col0 + rA) * K_D + kk;

  // Fragment read offsets (within one k-sub buffer).
  const int lr = lane & 15;
  const int lk = (lane >> 4) * 8;
  const int aOff = (wm * 64 + lr) * 32 + lk;
  const int bOff = (wn * 64 + lr) * 32 + lk;

  f32x4 fin[4][4];
#pragma unroll
  for (int m = 0; m < 4; ++m)
#pragma unroll
    for (int h = 0; h < 4; ++h) fin[m][h] = (f32x4){0.f, 0.f, 0.f, 0.f};

  f32x4 acc[4][8];
#pragma unroll
  for (int m = 0; m < 4; ++m)
#pragma unroll
    for (int n = 0; n < 8; ++n) acc[m][n] = (f32x4){0.f, 0.f, 0.f, 0.f};

  // Stage k-sub sn into buffer q. sn = pair*32 + ks; pair stride = 2*N_H*K_D.
  auto STAGE = [&](int sn, int q) {
    const int k0 = (sn & 31) << 5;
    const size_t pOff = (size_t)(sn >> 5) << 22;
    load16_lds(aB + k0, &As[q][tid * 8]);
    load16_lds(aB + (size_t)128 * K_D + k0, &As[q][4096 + tid * 8]);
    load16_lds(bB + pOff + k0, &Bs[q][tid * 8]);
    load16_lds(bB + pOff + (size_t)N_H * K_D + k0, &Bs[q][4096 + tid * 8]);
  };

  // Pair epilogue: fin += g_e0*LR(acc_e0 + be) + g_e1*LR(acc_e1 + be); acc=0.
  auto EPI = [&](int p) {
    const int e0 = p * 2;
#pragma unroll
    for (int m = 0; m < 4; ++m) {
#pragma unroll
      for (int j = 0; j < 4; ++j) {
        const int r = wm * 64 + m * 16 + (lane >> 4) * 4 + j;  // 0..255
        const float g0 = gS[r * 8 + e0];
        const float g1 = gS[r * 8 + e0 + 1];
#pragma unroll
        for (int h = 0; h < 4; ++h) {
          const int c = wn * 64 + h * 16 + lr;                 // 0..127
          float v0 = acc[m][h][j] + bS[e0 * 128 + c];
          v0 = (v0 >= 0.f) ? v0 : 0.01f * v0;
          float v1 = acc[m][4 + h][j] + bS[(e0 + 1) * 128 + c];
          v1 = (v1 >= 0.f) ? v1 : 0.01f * v1;
          fin[m][h][j] += g0 * v0 + g1 * v1;
        }
      }
    }
#pragma unroll
    for (int m = 0; m < 4; ++m)
#pragma unroll
      for (int n = 0; n < 8; ++n) acc[m][n] = (f32x4){0.f, 0.f, 0.f, 0.f};
  };

#define LGKM(N) asm volatile("s_waitcnt lgkmcnt(" #N ")" ::: "memory")

  // One phase. q = sn&3 (literal at every call site). doStage: sn+2 <= 127.
  auto PHASE = [&](int sn, int q, bool doStage, bool lastPhase) {
    if (lastPhase)
      asm volatile("s_waitcnt vmcnt(0)" ::: "memory");
    else
      asm volatile("s_waitcnt vmcnt(4)" ::: "memory");  // own sn loads landed
    __builtin_amdgcn_s_barrier();        // all waves' sn loads published
    __builtin_amdgcn_sched_barrier(0);   // reads stay below the barrier

    bf16x8 af[4], bfr[8];
#pragma unroll
    for (int m = 0; m < 4; ++m)
      af[m] = *(const bf16x8*)(&As[q][aOff + m * 512]);
#pragma unroll
    for (int n = 0; n < 8; ++n)
      bfr[n] = *(const bf16x8*)(&Bs[q][bOff + ((n >> 2) * 128 + (n & 3) * 16) * 32]);

    LGKM(7);                              // af[0..3]+bfr[0] retired
    __builtin_amdgcn_sched_barrier(0);
    if (doStage) STAGE(sn + 2, (q + 2) & 3);  // target last read at sn-2: safe

    __builtin_amdgcn_s_setprio(1);
#define MG(n)                                                   \
    _Pragma("unroll") for (int m = 0; m < 4; ++m)               \
        acc[m][n] = mfma16(af[m], bfr[n], acc[m][n]);
    MG(0)
    LGKM(6); __builtin_amdgcn_sched_barrier(0); MG(1)
    LGKM(5); __builtin_amdgcn_sched_barrier(0); MG(2)
    LGKM(4); __builtin_amdgcn_sched_barrier(0); MG(3)
    LGKM(3); __builtin_amdgcn_sched_barrier(0); MG(4)
    LGKM(2); __builtin_amdgcn_sched_barrier(0); MG(5)
    LGKM(1); __builtin_amdgcn_sched_barrier(0); MG(6)
    LGKM(0); __builtin_amdgcn_sched_barrier(0); MG(7)
#undef MG
    __builtin_amdgcn_s_setprio(0);

    if ((sn & 31) == 31) EPI(sn >> 5);
  };

  STAGE(0, 0);
  STAGE(1, 1);  // 8 own loads in flight; phase 0 waits vmcnt(4)

#pragma unroll 1
  for (int t4 = 0; t4 < 31; ++t4) {
    const int sn = t4 * 4;
    PHASE(sn + 0, 0, true, false);
    PHASE(sn + 1, 1, true, false);
    PHASE(sn + 2, 2, true, false);
    PHASE(sn + 3, 3, true, false);
  }
  PHASE(124, 0, true, false);   // stages 126
  PHASE(125, 1, true, false);   // stages 127
  PHASE(126, 2, false, false);  // vmcnt(4): 126 landed, 127 in flight
  PHASE(127, 3, false, true);   // vmcnt(0) + EPI(3)
#undef LGKM

  // C write (fp32 out)
#pragma unroll
  for (int m = 0; m < 4; ++m) {
#pragma unroll
    for (int j = 0; j < 4; ++j) {
      const size_t r = (size_t)(row0 + wm * 64 + m * 16 + (lane >> 4) * 4 + j);
#pragma unroll
      for (int h = 0; h < 4; ++h) {
        out[r * N_H + col0 + wn * 64 + h * 16 + lr] = fin[m][h][j];
      }
    }
  }
}

extern "C" void kernel_launch(void* const* d_in, const int* in_sizes, int n_in,
                              void* d_out, int out_size, void* d_ws, size_t ws_size,
                              hipStream_t stream) {
  const float* X  = (const float*)d_in[0];  // [8192,1024]
  const float* Wg = (const float*)d_in[1];  // [8,1024]
  const float* bg = (const float*)d_in[2];  // [8]
  const float* We = (const float*)d_in[3];  // [8,2048,1024]
  const float* be = (const float*)d_in[4];  // [8,2048]
  float* out = (float*)d_out;               // [8192,2048]

  // Workspace layout
  char* ws = (char*)d_ws;
  __bf16* Xb   = (__bf16*)(ws);                               // 16 MB
  __bf16* Wb   = (__bf16*)(ws + (size_t)16 * 1024 * 1024);    // 32 MB
  float*  gate = (float*)(ws + (size_t)48 * 1024 * 1024);     // 256 KB

  // 1) We f32 -> bf16
  cvt_kernel<<<2048, 256, 0, stream>>>(We, Wb, (N_E * N_H * K_D) / 4);

  // 2) gate probs + X f32->bf16 (fused)
  gate_kernel<<<M_TOK / 4, 256, 0, stream>>>(X, Wg, bg, gate, Xb);

  // 3) fused expert GEMM + gate-weighted reduction
  dim3 grid(M_TOK / 256, N_H / 128);
  moe_main<<<grid, 512, 0, stream>>>(Xb, Wb, gate, be, out);
}